// Round 6
// baseline (121.911 us; speedup 1.0000x reference)
//
#include <hip/hip_runtime.h>

#define ALPHA 0.1f
#define LOG2E 1.4426950408889634f

typedef __attribute__((ext_vector_type(8))) short bf16x8;
typedef __attribute__((ext_vector_type(4))) float f32x4;

// round-to-nearest-even f32 -> bf16 (returns bits in low 16)
__device__ __forceinline__ unsigned int f2bf(float f) {
    unsigned int u = __float_as_uint(f);
    return (u + 0x7FFFu + ((u >> 16) & 1u)) >> 16;
}

__global__ void mmd_zero(float* out) { out[0] = 0.f; }

// ---------------- prep: f32 x,y -> bf16 Z tiles (K-major chunks) + biases ----
// Z layout: z4[tile*1024 + kc*128 + r] = rows tile*128+r, elems kc*8..kc*8+7.
// bias[i] = -alpha*log2e*||z_i||^2 (from the bf16-rounded values).
__global__ __launch_bounds__(256) void mmd_prep(const float* __restrict__ x,
                                                const float* __restrict__ y,
                                                uint4* __restrict__ z4,
                                                float* __restrict__ bias, int N) {
    int t = blockIdx.x * 256 + threadIdx.x;   // one task per (row, kc), 2N*8 tasks
    int row = t >> 3, kc = t & 7;
    const float4* src = (row < N) ? (const float4*)x : (const float4*)y;
    int r = (row < N) ? row : row - N;
    float4 a = src[r * 16 + kc * 2];
    float4 b = src[r * 16 + kc * 2 + 1];
    unsigned int w0 = f2bf(a.x), w1 = f2bf(a.y), w2 = f2bf(a.z), w3 = f2bf(a.w);
    unsigned int w4 = f2bf(b.x), w5 = f2bf(b.y), w6 = f2bf(b.z), w7 = f2bf(b.w);
    uint4 pk;
    pk.x = w0 | (w1 << 16);
    pk.y = w2 | (w3 << 16);
    pk.z = w4 | (w5 << 16);
    pk.w = w6 | (w7 << 16);
    int tile = row >> 7, rr = row & 127;
    z4[tile * 1024 + kc * 128 + rr] = pk;

    // squared-norm partial over this thread's 8 bf16-rounded values
    float s = 0.f;
    unsigned int ws[8] = {w0, w1, w2, w3, w4, w5, w6, w7};
#pragma unroll
    for (int i = 0; i < 8; ++i) {
        float v = __uint_as_float(ws[i] << 16);
        s = fmaf(v, v, s);
    }
    // reduce across the 8 kc-threads of this row (lane groups of 8, aligned)
    s += __shfl_xor(s, 1);
    s += __shfl_xor(s, 2);
    s += __shfl_xor(s, 4);
    if (kc == 0) bias[row] = -ALPHA * LOG2E * s;
}

// ---------------- main: one gram pass per 128x128 tile pair -----------------
// total = sum_{bi<=bj} wgt * sum_{pairs} 2^(C2*dot + b_i + b_j),
// wgt = (diag?1:2) * sign(bi)*sign(bj), sign = +1 for x-tiles, -1 for y-tiles.
__global__ __launch_bounds__(256, 4) void mmd_main2(const uint4* __restrict__ z4,
                                                    const float* __restrict__ bias,
                                                    float* __restrict__ out,
                                                    int T2, int TX) {
    __shared__ uint4 ldsA[1024], ldsBt[1024];   // 2 x 16KB bf16 tiles
    __shared__ float ldsBiasA[128], ldsBiasB[128];
    __shared__ float ldsRed[4];

    // block -> upper-triangular (bi, bj), bi <= bj
    int u = blockIdx.x, bi = 0, rem = T2;
    while (u >= rem) { u -= rem; ++bi; --rem; }
    int bj = bi + u;

    int tid = threadIdx.x;
    int w = tid >> 6, l = tid & 63;

    // ---- stage 2 tiles via global_load_lds (16B, linear dest) ----
    const uint4* gA = z4 + bi * 1024;
    const uint4* gB = z4 + bj * 1024;
#pragma unroll
    for (int i = 0; i < 4; ++i) {
        int c = w * 4 + i;   // chunk 0..15, 64 uint4 each
        __builtin_amdgcn_global_load_lds(
            (const __attribute__((address_space(1))) void*)(gA + c * 64 + l),
            (__attribute__((address_space(3))) void*)&ldsA[c * 64], 16, 0, 0);
        __builtin_amdgcn_global_load_lds(
            (const __attribute__((address_space(1))) void*)(gB + c * 64 + l),
            (__attribute__((address_space(3))) void*)&ldsBt[c * 64], 16, 0, 0);
    }
    if (tid < 128) ldsBiasA[tid] = bias[bi * 128 + tid];
    else           ldsBiasB[tid - 128] = bias[bj * 128 + (tid - 128)];
    __syncthreads();

    int wr = w >> 1, wc = w & 1;          // 2x2 waves, each 64x64 output
    int lrow = l & 15, lk = l >> 4;

    // fragment loads: lane l takes row (l&15), k-chunk (l>>4) per 16x16x32
    bf16x8 af[4][2], bfr[4][2];
#pragma unroll
    for (int mb = 0; mb < 4; ++mb) {
#pragma unroll
        for (int kh = 0; kh < 2; ++kh) {
            int ar = wr * 64 + mb * 16 + lrow;
            int br = wc * 64 + mb * 16 + lrow;
            int kc = kh * 4 + lk;
            af[mb][kh]  = *(const bf16x8*)&ldsA[kc * 128 + ar];
            bfr[mb][kh] = *(const bf16x8*)&ldsBt[kc * 128 + br];
        }
    }

    f32x4 acc[4][4];
#pragma unroll
    for (int mb = 0; mb < 4; ++mb)
#pragma unroll
        for (int nb = 0; nb < 4; ++nb)
            acc[mb][nb] = (f32x4){0.f, 0.f, 0.f, 0.f};

#pragma unroll
    for (int mb = 0; mb < 4; ++mb) {
#pragma unroll
        for (int nb = 0; nb < 4; ++nb) {
            acc[mb][nb] = __builtin_amdgcn_mfma_f32_16x16x32_bf16(
                af[mb][0], bfr[nb][0], acc[mb][nb], 0, 0, 0);
            acc[mb][nb] = __builtin_amdgcn_mfma_f32_16x16x32_bf16(
                af[mb][1], bfr[nb][1], acc[mb][nb], 0, 0, 0);
        }
    }

    // epilogue: 2^(C2*dot + bA_row + bB_col), 4 partial sums to break the chain
    const float C2 = 2.f * ALPHA * LOG2E;
    float bA[4][4], bB[4];
#pragma unroll
    for (int mb = 0; mb < 4; ++mb)
#pragma unroll
        for (int q = 0; q < 4; ++q)
            bA[mb][q] = ldsBiasA[wr * 64 + mb * 16 + lk * 4 + q];
#pragma unroll
    for (int nb = 0; nb < 4; ++nb)
        bB[nb] = ldsBiasB[wc * 64 + nb * 16 + lrow];

    float sp[4] = {0.f, 0.f, 0.f, 0.f};
#pragma unroll
    for (int mb = 0; mb < 4; ++mb) {
#pragma unroll
        for (int nb = 0; nb < 4; ++nb) {
#pragma unroll
            for (int q = 0; q < 4; ++q) {
                float arg = fmaf(C2, acc[mb][nb][q], bA[mb][q] + bB[nb]);
                sp[q] += __builtin_amdgcn_exp2f(arg);
            }
        }
    }
    float stot = (sp[0] + sp[1]) + (sp[2] + sp[3]);

#pragma unroll
    for (int off = 32; off > 0; off >>= 1)
        stot += __shfl_down(stot, off, 64);
    if (l == 0) ldsRed[w] = stot;
    __syncthreads();
    if (tid == 0) {
        float wgt = (bi == bj) ? 1.f : 2.f;
        int sgn = ((bi < TX) ^ (bj < TX)) ? -1 : 1;
        atomicAdd(out, (float)sgn * wgt * (ldsRed[0] + ldsRed[1] + ldsRed[2] + ldsRed[3]));
    }
}

// ---------------- fallback (round-2 proven kernel, used if ws too small) ----
__global__ __launch_bounds__(256) void mmd_main(const float* __restrict__ x,
                                                const float* __restrict__ y,
                                                float* __restrict__ out, int T) {
    __shared__ uint4 ldsT[4][1024];
    __shared__ float ldsB[4][128];
    __shared__ float ldsRed[4];

    int u = blockIdx.x, bi = 0, rem = T;
    while (u >= rem) { u -= rem; ++bi; --rem; }
    int bj = bi + u;
    bool diag = (bi == bj);

    int tid = threadIdx.x;
    int RI = bi * 128, RJ = bj * 128;

    const float4* x4 = (const float4*)x;
    const float4* y4 = (const float4*)y;
#pragma unroll
    for (int p = 0; p < 16; ++p) {
        int task = p * 256 + tid;
        int buf = task >> 10;
        int q = task & 1023;
        int row = q >> 3, kc = q & 7;
        int base = (buf & 1) ? RJ : RI;
        const float4* src = (buf < 2) ? x4 : y4;
        float4 a = src[(base + row) * 16 + kc * 2];
        float4 b = src[(base + row) * 16 + kc * 2 + 1];
        uint4 pk;
        pk.x = f2bf(a.x) | (f2bf(a.y) << 16);
        pk.y = f2bf(a.z) | (f2bf(a.w) << 16);
        pk.z = f2bf(b.x) | (f2bf(b.y) << 16);
        pk.w = f2bf(b.z) | (f2bf(b.w) << 16);
        ldsT[buf][kc * 128 + row] = pk;
    }
    __syncthreads();

#pragma unroll
    for (int p = 0; p < 2; ++p) {
        int task = p * 256 + tid;
        int buf = task >> 7, row = task & 127;
        float s = 0.f;
#pragma unroll
        for (int kc = 0; kc < 8; ++kc) {
            uint4 v = ldsT[buf][kc * 128 + row];
            unsigned int wds[4] = {v.x, v.y, v.z, v.w};
#pragma unroll
            for (int i = 0; i < 4; ++i) {
                float lo = __uint_as_float(wds[i] << 16);
                float hi = __uint_as_float(wds[i] & 0xFFFF0000u);
                s = fmaf(lo, lo, s);
                s = fmaf(hi, hi, s);
            }
        }
        ldsB[buf][row] = -ALPHA * LOG2E * s;
    }
    __syncthreads();

    int w = tid >> 6, l = tid & 63;
    int wr = w >> 1, wc = w & 1;
    int lrow = l & 15, lk = l >> 4;

    const int aBufs[4] = {0, 2, 0, 1};
    const int bBufs[4] = {1, 3, 3, 2};
    float wKL = diag ? 1.f : 2.f;
    const float wts[4] = {wKL, wKL, -2.f, -2.f};
    int npass = diag ? 3 : 4;

    const float C2 = 2.f * ALPHA * LOG2E;
    float stot = 0.f;

    for (int ps = 0; ps < npass; ++ps) {
        int ab = aBufs[ps], bb = bBufs[ps];
        bf16x8 af[4][2], bfr[4][2];
#pragma unroll
        for (int mb = 0; mb < 4; ++mb) {
#pragma unroll
            for (int kh = 0; kh < 2; ++kh) {
                int ar = wr * 64 + mb * 16 + lrow;
                int br = wc * 64 + mb * 16 + lrow;
                int kc = kh * 4 + lk;
                af[mb][kh]  = *(const bf16x8*)&ldsT[ab][kc * 128 + ar];
                bfr[mb][kh] = *(const bf16x8*)&ldsT[bb][kc * 128 + br];
            }
        }
        f32x4 acc[4][4];
#pragma unroll
        for (int mb = 0; mb < 4; ++mb)
#pragma unroll
            for (int nb = 0; nb < 4; ++nb)
                acc[mb][nb] = (f32x4){0.f, 0.f, 0.f, 0.f};
#pragma unroll
        for (int mb = 0; mb < 4; ++mb) {
#pragma unroll
            for (int nb = 0; nb < 4; ++nb) {
                acc[mb][nb] = __builtin_amdgcn_mfma_f32_16x16x32_bf16(
                    af[mb][0], bfr[nb][0], acc[mb][nb], 0, 0, 0);
                acc[mb][nb] = __builtin_amdgcn_mfma_f32_16x16x32_bf16(
                    af[mb][1], bfr[nb][1], acc[mb][nb], 0, 0, 0);
            }
        }
        float bA[4][4], bB[4];
#pragma unroll
        for (int mb = 0; mb < 4; ++mb)
#pragma unroll
            for (int q = 0; q < 4; ++q)
                bA[mb][q] = ldsB[ab][wr * 64 + mb * 16 + lk * 4 + q];
#pragma unroll
        for (int nb = 0; nb < 4; ++nb)
            bB[nb] = ldsB[bb][wc * 64 + nb * 16 + lrow];
        float sp = 0.f;
#pragma unroll
        for (int mb = 0; mb < 4; ++mb) {
#pragma unroll
            for (int nb = 0; nb < 4; ++nb) {
#pragma unroll
                for (int q = 0; q < 4; ++q) {
                    float arg = fmaf(C2, acc[mb][nb][q], bA[mb][q] + bB[nb]);
                    sp += __builtin_amdgcn_exp2f(arg);
                }
            }
        }
        stot = fmaf(wts[ps], sp, stot);
    }

#pragma unroll
    for (int off = 32; off > 0; off >>= 1)
        stot += __shfl_down(stot, off, 64);
    if (l == 0) ldsRed[w] = stot;
    __syncthreads();
    if (tid == 0)
        atomicAdd(out, ldsRed[0] + ldsRed[1] + ldsRed[2] + ldsRed[3]);
}

extern "C" void kernel_launch(void* const* d_in, const int* in_sizes, int n_in,
                              void* d_out, int out_size, void* d_ws, size_t ws_size,
                              hipStream_t stream) {
    (void)n_in; (void)out_size;
    const float* x = (const float*)d_in[0];
    const float* y = (const float*)d_in[1];
    float* out = (float*)d_out;

    int N = in_sizes[0] / 64;               // 8192
    size_t zBytes = (size_t)2 * N * 128;    // 2N rows x 128B bf16
    size_t need = zBytes + (size_t)2 * N * 4;

    hipLaunchKernelGGL(mmd_zero, dim3(1), dim3(1), 0, stream, out);

    if (ws_size >= need) {
        uint4* z4 = (uint4*)d_ws;
        float* bias = (float*)((char*)d_ws + zBytes);
        int T2 = (2 * N) / 128;             // 128 tiles over Z
        int TX = N / 128;                   // first TX tiles are x
        int prepBlocks = (2 * N * 8) / 256; // 512
        int mainBlocks = T2 * (T2 + 1) / 2; // 8256
        hipLaunchKernelGGL(mmd_prep, dim3(prepBlocks), dim3(256), 0, stream,
                           x, y, z4, bias, N);
        hipLaunchKernelGGL(mmd_main2, dim3(mainBlocks), dim3(256), 0, stream,
                           z4, bias, out, T2, TX);
    } else {
        int T = N / 128;
        int nblocks = T * (T + 1) / 2;
        hipLaunchKernelGGL(mmd_main, dim3(nblocks), dim3(256), 0, stream,
                           x, y, out, T);
    }
}

// Round 8
// 49.474 us; speedup vs baseline: 2.4641x; 2.4641x over previous
//
#include <hip/hip_runtime.h>

#define ALPHA 0.1f
#define LOG2E 1.4426950408889634f
#define NJ 4

typedef __attribute__((ext_vector_type(8))) short bf16x8;
typedef __attribute__((ext_vector_type(4))) float f32x4;

// round-to-nearest-even f32 -> bf16 (returns bits in low 16)
__device__ __forceinline__ unsigned int f2bf(float f) {
    unsigned int u = __float_as_uint(f);
    return (u + 0x7FFFu + ((u >> 16) & 1u)) >> 16;
}

__global__ void mmd_zero(float* out) { out[0] = 0.f; }

// ---------------- prep: f32 x,y -> bf16 Z tiles (K-major chunks) + biases ----
// Z layout: z4[tile*1024 + kc*128 + r] = rows tile*128+r, elems kc*8..kc*8+7.
// bias[i] = -alpha*log2e*||z_i||^2 (from the bf16-rounded values).
__global__ __launch_bounds__(256) void mmd_prep(const float* __restrict__ x,
                                                const float* __restrict__ y,
                                                uint4* __restrict__ z4,
                                                float* __restrict__ bias, int N) {
    int t = blockIdx.x * 256 + threadIdx.x;   // one task per (row, kc), 2N*8 tasks
    int row = t >> 3, kc = t & 7;
    const float4* src = (row < N) ? (const float4*)x : (const float4*)y;
    int r = (row < N) ? row : row - N;
    float4 a = src[r * 16 + kc * 2];
    float4 b = src[r * 16 + kc * 2 + 1];
    unsigned int w0 = f2bf(a.x), w1 = f2bf(a.y), w2 = f2bf(a.z), w3 = f2bf(a.w);
    unsigned int w4 = f2bf(b.x), w5 = f2bf(b.y), w6 = f2bf(b.z), w7 = f2bf(b.w);
    uint4 pk;
    pk.x = w0 | (w1 << 16);
    pk.y = w2 | (w3 << 16);
    pk.z = w4 | (w5 << 16);
    pk.w = w6 | (w7 << 16);
    int tile = row >> 7, rr = row & 127;
    z4[tile * 1024 + kc * 128 + rr] = pk;

    float s = 0.f;
    unsigned int ws[8] = {w0, w1, w2, w3, w4, w5, w6, w7};
#pragma unroll
    for (int i = 0; i < 8; ++i) {
        float v = __uint_as_float(ws[i] << 16);
        s = fmaf(v, v, s);
    }
    s += __shfl_xor(s, 1);
    s += __shfl_xor(s, 2);
    s += __shfl_xor(s, 4);
    if (kc == 0) bias[row] = -ALPHA * LOG2E * s;
}

// ---------------- main: bi-strip, NJ bj-tiles, double-buffered B staging ----
// Block handles A-tile bi vs bj in [j0, j0+nj). A staged once, A-frags + biasA
// hoisted to registers; B[j+1] prefetched (global_load_lds) under pass j's
// compute; the __syncthreads vmcnt-drain at pass end lands it for pass j+1.
__global__ __launch_bounds__(256, 3) void mmd_main3(const uint4* __restrict__ z4,
                                                    const float* __restrict__ bias,
                                                    float* __restrict__ out,
                                                    int T2, int TX) {
    __shared__ uint4 ldsA[1024];       // 16KB A tile
    __shared__ uint4 ldsB[2][1024];    // 2 x 16KB B tiles (double buffer)
    __shared__ float ldsRed[4];

    // block -> (bi, chunk): chunk c of row bi covers bj = bi + c*NJ ...
    int u = blockIdx.x, bi = 0;
    int per = (T2 + NJ - 1) / NJ;
    while (u >= per) { u -= per; ++bi; per = (T2 - bi + NJ - 1) / NJ; }
    int j0 = bi + u * NJ;
    int nj = min(NJ, T2 - j0);

    int tid = threadIdx.x;
    int w = tid >> 6, l = tid & 63;

    // ---- stage A + B0 via global_load_lds (16B, linear dest) ----
    const uint4* gA = z4 + bi * 1024;
    const uint4* gB0 = z4 + j0 * 1024;
#pragma unroll
    for (int i = 0; i < 4; ++i) {
        int c = w * 4 + i;   // 16 chunks x 64 uint4
        __builtin_amdgcn_global_load_lds(
            (const __attribute__((address_space(1))) void*)(gA + c * 64 + l),
            (__attribute__((address_space(3))) void*)&ldsA[c * 64], 16, 0, 0);
        __builtin_amdgcn_global_load_lds(
            (const __attribute__((address_space(1))) void*)(gB0 + c * 64 + l),
            (__attribute__((address_space(3))) void*)&ldsB[0][c * 64], 16, 0, 0);
    }
    __syncthreads();

    int wr = w >> 1, wc = w & 1;          // 2x2 waves, each 64x64 output
    int lrow = l & 15, lk = l >> 4;

    // ---- A fragments + biasA hoisted (A fixed for whole block) ----
    bf16x8 af[4][2];
#pragma unroll
    for (int mb = 0; mb < 4; ++mb)
#pragma unroll
        for (int kh = 0; kh < 2; ++kh)
            af[mb][kh] = *(const bf16x8*)&ldsA[(kh * 4 + lk) * 128 +
                                               wr * 64 + mb * 16 + lrow];
    float bA[4][4];
#pragma unroll
    for (int mb = 0; mb < 4; ++mb)
#pragma unroll
        for (int q = 0; q < 4; ++q)
            bA[mb][q] = bias[bi * 128 + wr * 64 + mb * 16 + lk * 4 + q];

    const float C2 = 2.f * ALPHA * LOG2E;
    float stot = 0.f;

    for (int j = 0; j < nj; ++j) {
        int cur = j & 1;
        // prefetch next B tile into the other buffer (read-safe: last touched
        // in pass j-1, which completed before the barrier we just crossed)
        if (j + 1 < nj) {
            const uint4* gBn = z4 + (j0 + j + 1) * 1024;
#pragma unroll
            for (int i = 0; i < 4; ++i) {
                int c = w * 4 + i;
                __builtin_amdgcn_global_load_lds(
                    (const __attribute__((address_space(1))) void*)(gBn + c * 64 + l),
                    (__attribute__((address_space(3))) void*)&ldsB[cur ^ 1][c * 64],
                    16, 0, 0);
            }
        }
        int bj = j0 + j;

        float bB[4];
#pragma unroll
        for (int nb = 0; nb < 4; ++nb)
            bB[nb] = bias[bj * 128 + wc * 64 + nb * 16 + lrow];

        bf16x8 bfr[4][2];
#pragma unroll
        for (int nb = 0; nb < 4; ++nb)
#pragma unroll
            for (int kh = 0; kh < 2; ++kh)
                bfr[nb][kh] = *(const bf16x8*)&ldsB[cur][(kh * 4 + lk) * 128 +
                                                         wc * 64 + nb * 16 + lrow];

        f32x4 acc[4][4];
#pragma unroll
        for (int mb = 0; mb < 4; ++mb)
#pragma unroll
            for (int nb = 0; nb < 4; ++nb)
                acc[mb][nb] = (f32x4){0.f, 0.f, 0.f, 0.f};

#pragma unroll
        for (int mb = 0; mb < 4; ++mb) {
#pragma unroll
            for (int nb = 0; nb < 4; ++nb) {
                acc[mb][nb] = __builtin_amdgcn_mfma_f32_16x16x32_bf16(
                    af[mb][0], bfr[nb][0], acc[mb][nb], 0, 0, 0);
                acc[mb][nb] = __builtin_amdgcn_mfma_f32_16x16x32_bf16(
                    af[mb][1], bfr[nb][1], acc[mb][nb], 0, 0, 0);
            }
        }

        float sp[4] = {0.f, 0.f, 0.f, 0.f};
#pragma unroll
        for (int mb = 0; mb < 4; ++mb) {
#pragma unroll
            for (int nb = 0; nb < 4; ++nb) {
#pragma unroll
                for (int q = 0; q < 4; ++q) {
                    float arg = fmaf(C2, acc[mb][nb][q], bA[mb][q] + bB[nb]);
                    sp[q] += __builtin_amdgcn_exp2f(arg);
                }
            }
        }
        float wgt = ((bj == bi) ? 1.f : 2.f) *
                    (((bi < TX) != (bj < TX)) ? -1.f : 1.f);
        stot = fmaf(wgt, (sp[0] + sp[1]) + (sp[2] + sp[3]), stot);

        __syncthreads();   // drains prefetch vmcnt + guards ldsB reuse
    }

    // ---- reduce: wave shuffle -> LDS -> one atomic per block ----
#pragma unroll
    for (int off = 32; off > 0; off >>= 1)
        stot += __shfl_down(stot, off, 64);
    if (l == 0) ldsRed[w] = stot;
    __syncthreads();
    if (tid == 0)
        atomicAdd(out, ldsRed[0] + ldsRed[1] + ldsRed[2] + ldsRed[3]);
}

// ---------------- fallback (round-2 proven kernel, used if ws too small) ----
__global__ __launch_bounds__(256) void mmd_main(const float* __restrict__ x,
                                                const float* __restrict__ y,
                                                float* __restrict__ out, int T) {
    __shared__ uint4 ldsT[4][1024];
    __shared__ float ldsB[4][128];
    __shared__ float ldsRed[4];

    int u = blockIdx.x, bi = 0, rem = T;
    while (u >= rem) { u -= rem; ++bi; --rem; }
    int bj = bi + u;
    bool diag = (bi == bj);

    int tid = threadIdx.x;
    int RI = bi * 128, RJ = bj * 128;

    const float4* x4 = (const float4*)x;
    const float4* y4 = (const float4*)y;
#pragma unroll
    for (int p = 0; p < 16; ++p) {
        int task = p * 256 + tid;
        int buf = task >> 10;
        int q = task & 1023;
        int row = q >> 3, kc = q & 7;
        int base = (buf & 1) ? RJ : RI;
        const float4* src = (buf < 2) ? x4 : y4;
        float4 a = src[(base + row) * 16 + kc * 2];
        float4 b = src[(base + row) * 16 + kc * 2 + 1];
        uint4 pk;
        pk.x = f2bf(a.x) | (f2bf(a.y) << 16);
        pk.y = f2bf(a.z) | (f2bf(a.w) << 16);
        pk.z = f2bf(b.x) | (f2bf(b.y) << 16);
        pk.w = f2bf(b.z) | (f2bf(b.w) << 16);
        ldsT[buf][kc * 128 + row] = pk;
    }
    __syncthreads();

#pragma unroll
    for (int p = 0; p < 2; ++p) {
        int task = p * 256 + tid;
        int buf = task >> 7, row = task & 127;
        float s = 0.f;
#pragma unroll
        for (int kc = 0; kc < 8; ++kc) {
            uint4 v = ldsT[buf][kc * 128 + row];
            unsigned int wds[4] = {v.x, v.y, v.z, v.w};
#pragma unroll
            for (int i = 0; i < 4; ++i) {
                float lo = __uint_as_float(wds[i] << 16);
                float hi = __uint_as_float(wds[i] & 0xFFFF0000u);
                s = fmaf(lo, lo, s);
                s = fmaf(hi, hi, s);
            }
        }
        ldsB[buf][row] = -ALPHA * LOG2E * s;
    }
    __syncthreads();

    int w = tid >> 6, l = tid & 63;
    int wr = w >> 1, wc = w & 1;
    int lrow = l & 15, lk = l >> 4;

    const int aBufs[4] = {0, 2, 0, 1};
    const int bBufs[4] = {1, 3, 3, 2};
    float wKL = diag ? 1.f : 2.f;
    const float wts[4] = {wKL, wKL, -2.f, -2.f};
    int npass = diag ? 3 : 4;

    const float C2 = 2.f * ALPHA * LOG2E;
    float stot = 0.f;

    for (int ps = 0; ps < npass; ++ps) {
        int ab = aBufs[ps], bb = bBufs[ps];
        bf16x8 af[4][2], bfr[4][2];
#pragma unroll
        for (int mb = 0; mb < 4; ++mb) {
#pragma unroll
            for (int kh = 0; kh < 2; ++kh) {
                int ar = wr * 64 + mb * 16 + lrow;
                int br = wc * 64 + mb * 16 + lrow;
                int kc = kh * 4 + lk;
                af[mb][kh]  = *(const bf16x8*)&ldsT[ab][kc * 128 + ar];
                bfr[mb][kh] = *(const bf16x8*)&ldsT[bb][kc * 128 + br];
            }
        }
        f32x4 acc[4][4];
#pragma unroll
        for (int mb = 0; mb < 4; ++mb)
#pragma unroll
            for (int nb = 0; nb < 4; ++nb)
                acc[mb][nb] = (f32x4){0.f, 0.f, 0.f, 0.f};
#pragma unroll
        for (int mb = 0; mb < 4; ++mb) {
#pragma unroll
            for (int nb = 0; nb < 4; ++nb) {
                acc[mb][nb] = __builtin_amdgcn_mfma_f32_16x16x32_bf16(
                    af[mb][0], bfr[nb][0], acc[mb][nb], 0, 0, 0);
                acc[mb][nb] = __builtin_amdgcn_mfma_f32_16x16x32_bf16(
                    af[mb][1], bfr[nb][1], acc[mb][nb], 0, 0, 0);
            }
        }
        float bA[4][4], bB[4];
#pragma unroll
        for (int mb = 0; mb < 4; ++mb)
#pragma unroll
            for (int q = 0; q < 4; ++q)
                bA[mb][q] = ldsB[ab][wr * 64 + mb * 16 + lk * 4 + q];
#pragma unroll
        for (int nb = 0; nb < 4; ++nb)
            bB[nb] = ldsB[bb][wc * 64 + nb * 16 + lrow];
        float sp = 0.f;
#pragma unroll
        for (int mb = 0; mb < 4; ++mb) {
#pragma unroll
            for (int nb = 0; nb < 4; ++nb) {
#pragma unroll
                for (int q = 0; q < 4; ++q) {
                    float arg = fmaf(C2, acc[mb][nb][q], bA[mb][q] + bB[nb]);
                    sp += __builtin_amdgcn_exp2f(arg);
                }
            }
        }
        stot = fmaf(wts[ps], sp, stot);
    }

#pragma unroll
    for (int off = 32; off > 0; off >>= 1)
        stot += __shfl_down(stot, off, 64);
    if (l == 0) ldsRed[w] = stot;
    __syncthreads();
    if (tid == 0)
        atomicAdd(out, ldsRed[0] + ldsRed[1] + ldsRed[2] + ldsRed[3]);
}

extern "C" void kernel_launch(void* const* d_in, const int* in_sizes, int n_in,
                              void* d_out, int out_size, void* d_ws, size_t ws_size,
                              hipStream_t stream) {
    (void)n_in; (void)out_size;
    const float* x = (const float*)d_in[0];
    const float* y = (const float*)d_in[1];
    float* out = (float*)d_out;

    int N = in_sizes[0] / 64;               // 8192
    size_t zBytes = (size_t)2 * N * 128;    // 2N rows x 128B bf16
    size_t need = zBytes + (size_t)2 * N * 4;

    hipLaunchKernelGGL(mmd_zero, dim3(1), dim3(1), 0, stream, out);

    if (ws_size >= need) {
        uint4* z4 = (uint4*)d_ws;
        float* bias = (float*)((char*)d_ws + zBytes);
        int T2 = (2 * N) / 128;             // 128 tiles over Z
        int TX = N / 128;                   // first TX tiles are x
        int prepBlocks = (2 * N * 8) / 256; // 512
        int mainBlocks = 0;
        for (int bi = 0; bi < T2; ++bi) mainBlocks += (T2 - bi + NJ - 1) / NJ;
        hipLaunchKernelGGL(mmd_prep, dim3(prepBlocks), dim3(256), 0, stream,
                           x, y, z4, bias, N);
        hipLaunchKernelGGL(mmd_main3, dim3(mainBlocks), dim3(256), 0, stream,
                           z4, bias, out, T2, TX);
    } else {
        int T = N / 128;
        int nblocks = T * (T + 1) / 2;
        hipLaunchKernelGGL(mmd_main, dim3(nblocks), dim3(256), 0, stream,
                           x, y, out, T);
    }
}

// Round 9
// 44.231 us; speedup vs baseline: 2.7562x; 1.1185x over previous
//
#include <hip/hip_runtime.h>

#define ALPHA 0.1f
#define LOG2E 1.4426950408889634f
#define NJ 4

typedef __attribute__((ext_vector_type(8))) short bf16x8;
typedef __attribute__((ext_vector_type(4))) float f32x4;

// round-to-nearest-even f32 -> bf16 (returns bits in low 16)
__device__ __forceinline__ unsigned int f2bf(float f) {
    unsigned int u = __float_as_uint(f);
    return (u + 0x7FFFu + ((u >> 16) & 1u)) >> 16;
}

__global__ void mmd_zero(float* out) { out[0] = 0.f; }

// ---------------- prep: f32 x,y -> bf16 Z tiles (K-major chunks) + biases ----
// Z layout: z4[tile*1024 + kc*128 + r] = rows tile*128+r, elems kc*8..kc*8+7.
// bias[i] = -alpha*log2e*||z_i||^2 (from the bf16-rounded values).
// Also zeroes out[0] (prep dispatch completes before main starts).
__global__ __launch_bounds__(256) void mmd_prep(const float* __restrict__ x,
                                                const float* __restrict__ y,
                                                uint4* __restrict__ z4,
                                                float* __restrict__ bias,
                                                float* __restrict__ out, int N) {
    int t = blockIdx.x * 256 + threadIdx.x;   // one task per (row, kc), 2N*8 tasks
    if (t == 0) out[0] = 0.f;
    int row = t >> 3, kc = t & 7;
    const float4* src = (row < N) ? (const float4*)x : (const float4*)y;
    int r = (row < N) ? row : row - N;
    float4 a = src[r * 16 + kc * 2];
    float4 b = src[r * 16 + kc * 2 + 1];
    unsigned int w0 = f2bf(a.x), w1 = f2bf(a.y), w2 = f2bf(a.z), w3 = f2bf(a.w);
    unsigned int w4 = f2bf(b.x), w5 = f2bf(b.y), w6 = f2bf(b.z), w7 = f2bf(b.w);
    uint4 pk;
    pk.x = w0 | (w1 << 16);
    pk.y = w2 | (w3 << 16);
    pk.z = w4 | (w5 << 16);
    pk.w = w6 | (w7 << 16);
    int tile = row >> 7, rr = row & 127;
    z4[tile * 1024 + kc * 128 + rr] = pk;

    float s = 0.f;
    unsigned int ws[8] = {w0, w1, w2, w3, w4, w5, w6, w7};
#pragma unroll
    for (int i = 0; i < 8; ++i) {
        float v = __uint_as_float(ws[i] << 16);
        s = fmaf(v, v, s);
    }
    s += __shfl_xor(s, 1);
    s += __shfl_xor(s, 2);
    s += __shfl_xor(s, 4);
    if (kc == 0) bias[row] = -ALPHA * LOG2E * s;
}

// ---------------- main: no LDS, no barriers — direct L2 fragment loads -----
// Block = bi-strip of NJ bj-tiles. A-frags + A-bias in registers for the whole
// block; per pass, B-frags loaded straight from global (Z is 2MB, L2-resident,
// 16B/lane coalesced). Pass split into two 64x32 half-passes to keep acc at
// 32 regs. Epilogue: term = exp2(C2*dot + bA) * exp2(bB)  (bB folded as a
// multiplicative factor -> 2 VALU + 1 trans per term).
__global__ __launch_bounds__(256, 4) void mmd_main4(const uint4* __restrict__ z4,
                                                    const float* __restrict__ bias,
                                                    float* __restrict__ out,
                                                    int T2, int TX) {
    __shared__ float ldsRed[4];

    // block -> (bi, strip): strip u covers bj = bi + u*NJ ...
    int u = blockIdx.x, bi = 0;
    int per = (T2 + NJ - 1) / NJ;
    while (u >= per) { u -= per; ++bi; per = (T2 - bi + NJ - 1) / NJ; }
    int j0 = bi + u * NJ;
    int nj = min(NJ, T2 - j0);

    int tid = threadIdx.x;
    int w = tid >> 6, l = tid & 63;
    int wr = w >> 1, wc = w & 1;          // 2x2 waves, each 64x64 output
    int lrow = l & 15, lk = l >> 4;

    // ---- A fragments + A-bias, direct from global, live all block ----
    const uint4* gA = z4 + bi * 1024;
    bf16x8 af[4][2];
#pragma unroll
    for (int mb = 0; mb < 4; ++mb)
#pragma unroll
        for (int kh = 0; kh < 2; ++kh)
            af[mb][kh] = *(const bf16x8*)(gA + (kh * 4 + lk) * 128 +
                                          wr * 64 + mb * 16 + lrow);
    float bA[4][4];
#pragma unroll
    for (int mb = 0; mb < 4; ++mb)
#pragma unroll
        for (int q = 0; q < 4; ++q)
            bA[mb][q] = bias[bi * 128 + wr * 64 + mb * 16 + lk * 4 + q];

    const float C2 = 2.f * ALPHA * LOG2E;
    float stot = 0.f;

    for (int j = 0; j < nj; ++j) {
        int bj = j0 + j;
        const uint4* gB = z4 + bj * 1024;
        const float* biasB = bias + bj * 128 + wc * 64 + lrow;
        float sp[4] = {0.f, 0.f, 0.f, 0.f};

#pragma unroll
        for (int h = 0; h < 2; ++h) {       // two 64x32 half-passes
            bf16x8 bfr[2][2];
#pragma unroll
            for (int nb = 0; nb < 2; ++nb)
#pragma unroll
                for (int kh = 0; kh < 2; ++kh)
                    bfr[nb][kh] = *(const bf16x8*)(gB + (kh * 4 + lk) * 128 +
                                                   wc * 64 + (h * 2 + nb) * 16 + lrow);
            float ebB[2];
#pragma unroll
            for (int nb = 0; nb < 2; ++nb)
                ebB[nb] = __builtin_amdgcn_exp2f(biasB[(h * 2 + nb) * 16]);

            f32x4 acc[4][2];
#pragma unroll
            for (int mb = 0; mb < 4; ++mb)
#pragma unroll
                for (int nb = 0; nb < 2; ++nb)
                    acc[mb][nb] = (f32x4){0.f, 0.f, 0.f, 0.f};

#pragma unroll
            for (int mb = 0; mb < 4; ++mb) {
#pragma unroll
                for (int nb = 0; nb < 2; ++nb) {
                    acc[mb][nb] = __builtin_amdgcn_mfma_f32_16x16x32_bf16(
                        af[mb][0], bfr[nb][0], acc[mb][nb], 0, 0, 0);
                    acc[mb][nb] = __builtin_amdgcn_mfma_f32_16x16x32_bf16(
                        af[mb][1], bfr[nb][1], acc[mb][nb], 0, 0, 0);
                }
            }

#pragma unroll
            for (int mb = 0; mb < 4; ++mb)
#pragma unroll
                for (int nb = 0; nb < 2; ++nb)
#pragma unroll
                    for (int q = 0; q < 4; ++q) {
                        float e = __builtin_amdgcn_exp2f(
                            fmaf(C2, acc[mb][nb][q], bA[mb][q]));
                        sp[q] = fmaf(ebB[nb], e, sp[q]);
                    }
        }

        float wgt = ((bj == bi) ? 1.f : 2.f) *
                    (((bi < TX) != (bj < TX)) ? -1.f : 1.f);
        stot = fmaf(wgt, (sp[0] + sp[1]) + (sp[2] + sp[3]), stot);
    }

    // ---- reduce: wave shuffle -> LDS -> one atomic per block ----
#pragma unroll
    for (int off = 32; off > 0; off >>= 1)
        stot += __shfl_down(stot, off, 64);
    if (l == 0) ldsRed[w] = stot;
    __syncthreads();
    if (tid == 0)
        atomicAdd(out, ldsRed[0] + ldsRed[1] + ldsRed[2] + ldsRed[3]);
}

// ---------------- fallback (round-2 proven kernel, used if ws too small) ----
__global__ __launch_bounds__(256) void mmd_main(const float* __restrict__ x,
                                                const float* __restrict__ y,
                                                float* __restrict__ out, int T) {
    __shared__ uint4 ldsT[4][1024];
    __shared__ float ldsB[4][128];
    __shared__ float ldsRed[4];

    int u = blockIdx.x, bi = 0, rem = T;
    while (u >= rem) { u -= rem; ++bi; --rem; }
    int bj = bi + u;
    bool diag = (bi == bj);

    int tid = threadIdx.x;
    int RI = bi * 128, RJ = bj * 128;

    const float4* x4 = (const float4*)x;
    const float4* y4 = (const float4*)y;
#pragma unroll
    for (int p = 0; p < 16; ++p) {
        int task = p * 256 + tid;
        int buf = task >> 10;
        int q = task & 1023;
        int row = q >> 3, kc = q & 7;
        int base = (buf & 1) ? RJ : RI;
        const float4* src = (buf < 2) ? x4 : y4;
        float4 a = src[(base + row) * 16 + kc * 2];
        float4 b = src[(base + row) * 16 + kc * 2 + 1];
        uint4 pk;
        pk.x = f2bf(a.x) | (f2bf(a.y) << 16);
        pk.y = f2bf(a.z) | (f2bf(a.w) << 16);
        pk.z = f2bf(b.x) | (f2bf(b.y) << 16);
        pk.w = f2bf(b.z) | (f2bf(b.w) << 16);
        ldsT[buf][kc * 128 + row] = pk;
    }
    __syncthreads();

#pragma unroll
    for (int p = 0; p < 2; ++p) {
        int task = p * 256 + tid;
        int buf = task >> 7, row = task & 127;
        float s = 0.f;
#pragma unroll
        for (int kc = 0; kc < 8; ++kc) {
            uint4 v = ldsT[buf][kc * 128 + row];
            unsigned int wds[4] = {v.x, v.y, v.z, v.w};
#pragma unroll
            for (int i = 0; i < 4; ++i) {
                float lo = __uint_as_float(wds[i] << 16);
                float hi = __uint_as_float(wds[i] & 0xFFFF0000u);
                s = fmaf(lo, lo, s);
                s = fmaf(hi, hi, s);
            }
        }
        ldsB[buf][row] = -ALPHA * LOG2E * s;
    }
    __syncthreads();

    int w = tid >> 6, l = tid & 63;
    int wr = w >> 1, wc = w & 1;
    int lrow = l & 15, lk = l >> 4;

    const int aBufs[4] = {0, 2, 0, 1};
    const int bBufs[4] = {1, 3, 3, 2};
    float wKL = diag ? 1.f : 2.f;
    const float wts[4] = {wKL, wKL, -2.f, -2.f};
    int npass = diag ? 3 : 4;

    const float C2 = 2.f * ALPHA * LOG2E;
    float stot = 0.f;

    for (int ps = 0; ps < npass; ++ps) {
        int ab = aBufs[ps], bb = bBufs[ps];
        bf16x8 af[4][2], bfr[4][2];
#pragma unroll
        for (int mb = 0; mb < 4; ++mb) {
#pragma unroll
            for (int kh = 0; kh < 2; ++kh) {
                int ar = wr * 64 + mb * 16 + lrow;
                int br = wc * 64 + mb * 16 + lrow;
                int kc = kh * 4 + lk;
                af[mb][kh]  = *(const bf16x8*)&ldsT[ab][kc * 128 + ar];
                bfr[mb][kh] = *(const bf16x8*)&ldsT[bb][kc * 128 + br];
            }
        }
        f32x4 acc[4][4];
#pragma unroll
        for (int mb = 0; mb < 4; ++mb)
#pragma unroll
            for (int nb = 0; nb < 4; ++nb)
                acc[mb][nb] = (f32x4){0.f, 0.f, 0.f, 0.f};
#pragma unroll
        for (int mb = 0; mb < 4; ++mb) {
#pragma unroll
            for (int nb = 0; nb < 4; ++nb) {
                acc[mb][nb] = __builtin_amdgcn_mfma_f32_16x16x32_bf16(
                    af[mb][0], bfr[nb][0], acc[mb][nb], 0, 0, 0);
                acc[mb][nb] = __builtin_amdgcn_mfma_f32_16x16x32_bf16(
                    af[mb][1], bfr[nb][1], acc[mb][nb], 0, 0, 0);
            }
        }
        float bA[4][4], bB[4];
#pragma unroll
        for (int mb = 0; mb < 4; ++mb)
#pragma unroll
            for (int q = 0; q < 4; ++q)
                bA[mb][q] = ldsB[ab][wr * 64 + mb * 16 + lk * 4 + q];
#pragma unroll
        for (int nb = 0; nb < 4; ++nb)
            bB[nb] = ldsB[bb][wc * 64 + nb * 16 + lrow];
        float sp = 0.f;
#pragma unroll
        for (int mb = 0; mb < 4; ++mb) {
#pragma unroll
            for (int nb = 0; nb < 4; ++nb) {
#pragma unroll
                for (int q = 0; q < 4; ++q) {
                    float arg = fmaf(C2, acc[mb][nb][q], bA[mb][q] + bB[nb]);
                    sp += __builtin_amdgcn_exp2f(arg);
                }
            }
        }
        stot = fmaf(wts[ps], sp, stot);
    }

#pragma unroll
    for (int off = 32; off > 0; off >>= 1)
        stot += __shfl_down(stot, off, 64);
    if (l == 0) ldsRed[w] = stot;
    __syncthreads();
    if (tid == 0)
        atomicAdd(out, ldsRed[0] + ldsRed[1] + ldsRed[2] + ldsRed[3]);
}

extern "C" void kernel_launch(void* const* d_in, const int* in_sizes, int n_in,
                              void* d_out, int out_size, void* d_ws, size_t ws_size,
                              hipStream_t stream) {
    (void)n_in; (void)out_size;
    const float* x = (const float*)d_in[0];
    const float* y = (const float*)d_in[1];
    float* out = (float*)d_out;

    int N = in_sizes[0] / 64;               // 8192
    size_t zBytes = (size_t)2 * N * 128;    // 2N rows x 128B bf16
    size_t need = zBytes + (size_t)2 * N * 4;

    if (ws_size >= need) {
        uint4* z4 = (uint4*)d_ws;
        float* bias = (float*)((char*)d_ws + zBytes);
        int T2 = (2 * N) / 128;             // 128 tiles over Z
        int TX = N / 128;                   // first TX tiles are x
        int prepBlocks = (2 * N * 8) / 256; // 512
        int mainBlocks = 0;
        for (int bi = 0; bi < T2; ++bi) mainBlocks += (T2 - bi + NJ - 1) / NJ;
        hipLaunchKernelGGL(mmd_prep, dim3(prepBlocks), dim3(256), 0, stream,
                           x, y, z4, bias, out, N);
        hipLaunchKernelGGL(mmd_main4, dim3(mainBlocks), dim3(256), 0, stream,
                           z4, bias, out, T2, TX);
    } else {
        int T = N / 128;
        int nblocks = T * (T + 1) / 2;
        hipLaunchKernelGGL(mmd_zero, dim3(1), dim3(1), 0, stream, out);
        hipLaunchKernelGGL(mmd_main, dim3(nblocks), dim3(256), 0, stream,
                           x, y, out, T);
    }
}

// Round 10
// 38.012 us; speedup vs baseline: 3.2072x; 1.1636x over previous
//
#include <hip/hip_runtime.h>

#define ALPHA 0.1f
#define LOG2E 1.4426950408889634f
#define NJ 4

typedef __attribute__((ext_vector_type(8))) short bf16x8;
typedef __attribute__((ext_vector_type(4))) float f32x4;

// round-to-nearest-even f32 -> bf16 (returns bits in low 16)
__device__ __forceinline__ unsigned int f2bf(float f) {
    unsigned int u = __float_as_uint(f);
    return (u + 0x7FFFu + ((u >> 16) & 1u)) >> 16;
}

__global__ void mmd_zero(float* out) { out[0] = 0.f; }

// ---------------- prep: f32 x,y -> bf16 Z tiles (K-major chunks) + biases ----
// Z layout: z4[tile*1024 + kc*128 + r] = rows tile*128+r, elems kc*8..kc*8+7.
// bias[i] = -alpha*log2e*||z_i||^2 (from the bf16-rounded values).
__global__ __launch_bounds__(256) void mmd_prep(const float* __restrict__ x,
                                                const float* __restrict__ y,
                                                uint4* __restrict__ z4,
                                                float* __restrict__ bias, int N) {
    int t = blockIdx.x * 256 + threadIdx.x;   // one task per (row, kc), 2N*8 tasks
    int row = t >> 3, kc = t & 7;
    const float4* src = (row < N) ? (const float4*)x : (const float4*)y;
    int r = (row < N) ? row : row - N;
    float4 a = src[r * 16 + kc * 2];
    float4 b = src[r * 16 + kc * 2 + 1];
    unsigned int w0 = f2bf(a.x), w1 = f2bf(a.y), w2 = f2bf(a.z), w3 = f2bf(a.w);
    unsigned int w4 = f2bf(b.x), w5 = f2bf(b.y), w6 = f2bf(b.z), w7 = f2bf(b.w);
    uint4 pk;
    pk.x = w0 | (w1 << 16);
    pk.y = w2 | (w3 << 16);
    pk.z = w4 | (w5 << 16);
    pk.w = w6 | (w7 << 16);
    int tile = row >> 7, rr = row & 127;
    z4[tile * 1024 + kc * 128 + rr] = pk;

    float s = 0.f;
    unsigned int ws[8] = {w0, w1, w2, w3, w4, w5, w6, w7};
#pragma unroll
    for (int i = 0; i < 8; ++i) {
        float v = __uint_as_float(ws[i] << 16);
        s = fmaf(v, v, s);
    }
    s += __shfl_xor(s, 1);
    s += __shfl_xor(s, 2);
    s += __shfl_xor(s, 4);
    if (kc == 0) bias[row] = -ALPHA * LOG2E * s;
}

// ---------------- main: no LDS tiles, no atomics — partial per block --------
// Identical compute to round-9 mmd_main4; the ONLY change is the ending:
// plain store of the block partial to part[blockIdx.x] (atomic contention on
// out[0] was the suspected serial drain).
__global__ __launch_bounds__(256, 4) void mmd_main4(const uint4* __restrict__ z4,
                                                    const float* __restrict__ bias,
                                                    float* __restrict__ part,
                                                    int T2, int TX) {
    __shared__ float ldsRed[4];

    // block -> (bi, strip): strip u covers bj = bi + u*NJ ...
    int u = blockIdx.x, bi = 0;
    int per = (T2 + NJ - 1) / NJ;
    while (u >= per) { u -= per; ++bi; per = (T2 - bi + NJ - 1) / NJ; }
    int j0 = bi + u * NJ;
    int nj = min(NJ, T2 - j0);

    int tid = threadIdx.x;
    int w = tid >> 6, l = tid & 63;
    int wr = w >> 1, wc = w & 1;          // 2x2 waves, each 64x64 output
    int lrow = l & 15, lk = l >> 4;

    // ---- A fragments + A-bias, direct from global, live all block ----
    const uint4* gA = z4 + bi * 1024;
    bf16x8 af[4][2];
#pragma unroll
    for (int mb = 0; mb < 4; ++mb)
#pragma unroll
        for (int kh = 0; kh < 2; ++kh)
            af[mb][kh] = *(const bf16x8*)(gA + (kh * 4 + lk) * 128 +
                                          wr * 64 + mb * 16 + lrow);
    float bA[4][4];
#pragma unroll
    for (int mb = 0; mb < 4; ++mb)
#pragma unroll
        for (int q = 0; q < 4; ++q)
            bA[mb][q] = bias[bi * 128 + wr * 64 + mb * 16 + lk * 4 + q];

    const float C2 = 2.f * ALPHA * LOG2E;
    float stot = 0.f;

    for (int j = 0; j < nj; ++j) {
        int bj = j0 + j;
        const uint4* gB = z4 + bj * 1024;
        const float* biasB = bias + bj * 128 + wc * 64 + lrow;
        float sp[4] = {0.f, 0.f, 0.f, 0.f};

#pragma unroll
        for (int h = 0; h < 2; ++h) {       // two 64x32 half-passes
            bf16x8 bfr[2][2];
#pragma unroll
            for (int nb = 0; nb < 2; ++nb)
#pragma unroll
                for (int kh = 0; kh < 2; ++kh)
                    bfr[nb][kh] = *(const bf16x8*)(gB + (kh * 4 + lk) * 128 +
                                                   wc * 64 + (h * 2 + nb) * 16 + lrow);
            float ebB[2];
#pragma unroll
            for (int nb = 0; nb < 2; ++nb)
                ebB[nb] = __builtin_amdgcn_exp2f(biasB[(h * 2 + nb) * 16]);

            f32x4 acc[4][2];
#pragma unroll
            for (int mb = 0; mb < 4; ++mb)
#pragma unroll
                for (int nb = 0; nb < 2; ++nb)
                    acc[mb][nb] = (f32x4){0.f, 0.f, 0.f, 0.f};

#pragma unroll
            for (int mb = 0; mb < 4; ++mb) {
#pragma unroll
                for (int nb = 0; nb < 2; ++nb) {
                    acc[mb][nb] = __builtin_amdgcn_mfma_f32_16x16x32_bf16(
                        af[mb][0], bfr[nb][0], acc[mb][nb], 0, 0, 0);
                    acc[mb][nb] = __builtin_amdgcn_mfma_f32_16x16x32_bf16(
                        af[mb][1], bfr[nb][1], acc[mb][nb], 0, 0, 0);
                }
            }

#pragma unroll
            for (int mb = 0; mb < 4; ++mb)
#pragma unroll
                for (int nb = 0; nb < 2; ++nb)
#pragma unroll
                    for (int q = 0; q < 4; ++q) {
                        float e = __builtin_amdgcn_exp2f(
                            fmaf(C2, acc[mb][nb][q], bA[mb][q]));
                        sp[q] = fmaf(ebB[nb], e, sp[q]);
                    }
        }

        float wgt = ((bj == bi) ? 1.f : 2.f) *
                    (((bi < TX) != (bj < TX)) ? -1.f : 1.f);
        stot = fmaf(wgt, (sp[0] + sp[1]) + (sp[2] + sp[3]), stot);
    }

    // ---- reduce: wave shuffle -> LDS -> ONE PLAIN STORE per block ----
#pragma unroll
    for (int off = 32; off > 0; off >>= 1)
        stot += __shfl_down(stot, off, 64);
    if (l == 0) ldsRed[w] = stot;
    __syncthreads();
    if (tid == 0)
        part[blockIdx.x] = ldsRed[0] + ldsRed[1] + ldsRed[2] + ldsRed[3];
}

// ---------------- final: single-block sum of partials -> out[0] -------------
__global__ __launch_bounds__(1024) void mmd_reduce(const float* __restrict__ part,
                                                   float* __restrict__ out, int n) {
    __shared__ float red[16];
    int tid = threadIdx.x;
    float s = 0.f;
    for (int i = tid; i < n; i += 1024) s += part[i];
#pragma unroll
    for (int off = 32; off > 0; off >>= 1)
        s += __shfl_down(s, off, 64);
    int w = tid >> 6, l = tid & 63;
    if (l == 0) red[w] = s;
    __syncthreads();
    if (tid == 0) {
        float t = 0.f;
#pragma unroll
        for (int i = 0; i < 16; ++i) t += red[i];
        out[0] = t;
    }
}

// ---------------- fallback (round-2 proven kernel, used if ws too small) ----
__global__ __launch_bounds__(256) void mmd_main(const float* __restrict__ x,
                                                const float* __restrict__ y,
                                                float* __restrict__ out, int T) {
    __shared__ uint4 ldsT[4][1024];
    __shared__ float ldsB[4][128];
    __shared__ float ldsRed[4];

    int u = blockIdx.x, bi = 0, rem = T;
    while (u >= rem) { u -= rem; ++bi; --rem; }
    int bj = bi + u;
    bool diag = (bi == bj);

    int tid = threadIdx.x;
    int RI = bi * 128, RJ = bj * 128;

    const float4* x4 = (const float4*)x;
    const float4* y4 = (const float4*)y;
#pragma unroll
    for (int p = 0; p < 16; ++p) {
        int task = p * 256 + tid;
        int buf = task >> 10;
        int q = task & 1023;
        int row = q >> 3, kc = q & 7;
        int base = (buf & 1) ? RJ : RI;
        const float4* src = (buf < 2) ? x4 : y4;
        float4 a = src[(base + row) * 16 + kc * 2];
        float4 b = src[(base + row) * 16 + kc * 2 + 1];
        uint4 pk;
        pk.x = f2bf(a.x) | (f2bf(a.y) << 16);
        pk.y = f2bf(a.z) | (f2bf(a.w) << 16);
        pk.z = f2bf(b.x) | (f2bf(b.y) << 16);
        pk.w = f2bf(b.z) | (f2bf(b.w) << 16);
        ldsT[buf][kc * 128 + row] = pk;
    }
    __syncthreads();

#pragma unroll
    for (int p = 0; p < 2; ++p) {
        int task = p * 256 + tid;
        int buf = task >> 7, row = task & 127;
        float s = 0.f;
#pragma unroll
        for (int kc = 0; kc < 8; ++kc) {
            uint4 v = ldsT[buf][kc * 128 + row];
            unsigned int wds[4] = {v.x, v.y, v.z, v.w};
#pragma unroll
            for (int i = 0; i < 4; ++i) {
                float lo = __uint_as_float(wds[i] << 16);
                float hi = __uint_as_float(wds[i] & 0xFFFF0000u);
                s = fmaf(lo, lo, s);
                s = fmaf(hi, hi, s);
            }
        }
        ldsB[buf][row] = -ALPHA * LOG2E * s;
    }
    __syncthreads();

    int w = tid >> 6, l = tid & 63;
    int wr = w >> 1, wc = w & 1;
    int lrow = l & 15, lk = l >> 4;

    const int aBufs[4] = {0, 2, 0, 1};
    const int bBufs[4] = {1, 3, 3, 2};
    float wKL = diag ? 1.f : 2.f;
    const float wts[4] = {wKL, wKL, -2.f, -2.f};
    int npass = diag ? 3 : 4;

    const float C2 = 2.f * ALPHA * LOG2E;
    float stot = 0.f;

    for (int ps = 0; ps < npass; ++ps) {
        int ab = aBufs[ps], bb = bBufs[ps];
        bf16x8 af[4][2], bfr[4][2];
#pragma unroll
        for (int mb = 0; mb < 4; ++mb) {
#pragma unroll
            for (int kh = 0; kh < 2; ++kh) {
                int ar = wr * 64 + mb * 16 + lrow;
                int br = wc * 64 + mb * 16 + lrow;
                int kc = kh * 4 + lk;
                af[mb][kh]  = *(const bf16x8*)&ldsT[ab][kc * 128 + ar];
                bfr[mb][kh] = *(const bf16x8*)&ldsT[bb][kc * 128 + br];
            }
        }
        f32x4 acc[4][4];
#pragma unroll
        for (int mb = 0; mb < 4; ++mb)
#pragma unroll
            for (int nb = 0; nb < 4; ++nb)
                acc[mb][nb] = (f32x4){0.f, 0.f, 0.f, 0.f};
#pragma unroll
        for (int mb = 0; mb < 4; ++mb) {
#pragma unroll
            for (int nb = 0; nb < 4; ++nb) {
                acc[mb][nb] = __builtin_amdgcn_mfma_f32_16x16x32_bf16(
                    af[mb][0], bfr[nb][0], acc[mb][nb], 0, 0, 0);
                acc[mb][nb] = __builtin_amdgcn_mfma_f32_16x16x32_bf16(
                    af[mb][1], bfr[nb][1], acc[mb][nb], 0, 0, 0);
            }
        }
        float bA[4][4], bB[4];
#pragma unroll
        for (int mb = 0; mb < 4; ++mb)
#pragma unroll
            for (int q = 0; q < 4; ++q)
                bA[mb][q] = ldsB[ab][wr * 64 + mb * 16 + lk * 4 + q];
#pragma unroll
        for (int nb = 0; nb < 4; ++nb)
            bB[nb] = ldsB[bb][wc * 64 + nb * 16 + lrow];
        float sp = 0.f;
#pragma unroll
        for (int mb = 0; mb < 4; ++mb) {
#pragma unroll
            for (int nb = 0; nb < 4; ++nb) {
#pragma unroll
                for (int q = 0; q < 4; ++q) {
                    float arg = fmaf(C2, acc[mb][nb][q], bA[mb][q] + bB[nb]);
                    sp += __builtin_amdgcn_exp2f(arg);
                }
            }
        }
        stot = fmaf(wts[ps], sp, stot);
    }

#pragma unroll
    for (int off = 32; off > 0; off >>= 1)
        stot += __shfl_down(stot, off, 64);
    if (l == 0) ldsRed[w] = stot;
    __syncthreads();
    if (tid == 0)
        atomicAdd(out, ldsRed[0] + ldsRed[1] + ldsRed[2] + ldsRed[3]);
}

extern "C" void kernel_launch(void* const* d_in, const int* in_sizes, int n_in,
                              void* d_out, int out_size, void* d_ws, size_t ws_size,
                              hipStream_t stream) {
    (void)n_in; (void)out_size;
    const float* x = (const float*)d_in[0];
    const float* y = (const float*)d_in[1];
    float* out = (float*)d_out;

    int N = in_sizes[0] / 64;               // 8192
    int T2 = (2 * N) / 128;                 // 128 tiles over Z
    int TX = N / 128;
    int mainBlocks = 0;
    for (int bi = 0; bi < T2; ++bi) mainBlocks += (T2 - bi + NJ - 1) / NJ;

    size_t zBytes = (size_t)2 * N * 128;    // 2N rows x 128B bf16
    size_t bBytes = (size_t)2 * N * 4;
    size_t need = zBytes + bBytes + (size_t)mainBlocks * 4;

    if (ws_size >= need) {
        uint4* z4 = (uint4*)d_ws;
        float* bias = (float*)((char*)d_ws + zBytes);
        float* part = (float*)((char*)d_ws + zBytes + bBytes);
        int prepBlocks = (2 * N * 8) / 256; // 512
        hipLaunchKernelGGL(mmd_prep, dim3(prepBlocks), dim3(256), 0, stream,
                           x, y, z4, bias, N);
        hipLaunchKernelGGL(mmd_main4, dim3(mainBlocks), dim3(256), 0, stream,
                           z4, bias, part, T2, TX);
        hipLaunchKernelGGL(mmd_reduce, dim3(1), dim3(1024), 0, stream,
                           part, out, mainBlocks);
    } else {
        int T = N / 128;
        int nblocks = T * (T + 1) / 2;
        hipLaunchKernelGGL(mmd_zero, dim3(1), dim3(1), 0, stream, out);
        hipLaunchKernelGGL(mmd_main, dim3(nblocks), dim3(256), 0, stream,
                           x, y, out, T);
    }
}